// Round 1
// baseline (1472.586 us; speedup 1.0000x reference)
//
#include <hip/hip_runtime.h>

typedef __bf16 bf16x8 __attribute__((ext_vector_type(8)));
typedef float f32x4 __attribute__((ext_vector_type(4)));
typedef unsigned int u32x4 __attribute__((ext_vector_type(4)));

#define S_LEN 256
#define BATCH 64
#define HID   1024
#define NWG   256
#define SBH   (S_LEN * BATCH * HID)   /* 16777216 */
#define BH    (BATCH * HID)           /* 65536 */
/* bar layout (ints): cnt[4][8][256] at 0 (8192), root[4][256] at 8192 (1024). */
#define BAR_INTS 9216

__device__ __forceinline__ float sigm(float v) { return 1.0f / (1.0f + __expf(-v)); }
__device__ __forceinline__ float tanh_fast(float v) {
  float e = __expf(-2.0f * __builtin_fabsf(v));
  float r = (1.0f - e) / (1.0f + e);
  return __builtin_copysignf(r, v);
}

// Pack 8 f32 -> 8 bf16 (RNE via compiler cvt) into one 16B word.
__device__ __forceinline__ u32x4 cvt8(float4 a, float4 b) {
  union { unsigned short us[8]; u32x4 v; } r;
  r.us[0] = __builtin_bit_cast(unsigned short, (__bf16)a.x);
  r.us[1] = __builtin_bit_cast(unsigned short, (__bf16)a.y);
  r.us[2] = __builtin_bit_cast(unsigned short, (__bf16)a.z);
  r.us[3] = __builtin_bit_cast(unsigned short, (__bf16)a.w);
  r.us[4] = __builtin_bit_cast(unsigned short, (__bf16)b.x);
  r.us[5] = __builtin_bit_cast(unsigned short, (__bf16)b.y);
  r.us[6] = __builtin_bit_cast(unsigned short, (__bf16)b.z);
  r.us[7] = __builtin_bit_cast(unsigned short, (__bf16)b.w);
  return r.v;
}

// One asm block: 16 x global_load_dwordx4 from base %16 + kc*64B, then vmcnt(0).
// Early-clobber outputs + internal waitcnt => no compiler copy can read in-flight regs.
#define LOAD16_X4(dst, base, MODS)                                            \
  asm volatile(                                                               \
      "global_load_dwordx4 %0,  %16, off offset:0 " MODS "\n\t"               \
      "global_load_dwordx4 %1,  %16, off offset:64 " MODS "\n\t"              \
      "global_load_dwordx4 %2,  %16, off offset:128 " MODS "\n\t"             \
      "global_load_dwordx4 %3,  %16, off offset:192 " MODS "\n\t"             \
      "global_load_dwordx4 %4,  %16, off offset:256 " MODS "\n\t"             \
      "global_load_dwordx4 %5,  %16, off offset:320 " MODS "\n\t"             \
      "global_load_dwordx4 %6,  %16, off offset:384 " MODS "\n\t"             \
      "global_load_dwordx4 %7,  %16, off offset:448 " MODS "\n\t"             \
      "global_load_dwordx4 %8,  %16, off offset:512 " MODS "\n\t"             \
      "global_load_dwordx4 %9,  %16, off offset:576 " MODS "\n\t"             \
      "global_load_dwordx4 %10, %16, off offset:640 " MODS "\n\t"             \
      "global_load_dwordx4 %11, %16, off offset:704 " MODS "\n\t"             \
      "global_load_dwordx4 %12, %16, off offset:768 " MODS "\n\t"             \
      "global_load_dwordx4 %13, %16, off offset:832 " MODS "\n\t"             \
      "global_load_dwordx4 %14, %16, off offset:896 " MODS "\n\t"             \
      "global_load_dwordx4 %15, %16, off offset:960 " MODS "\n\t"             \
      "s_waitcnt vmcnt(0)"                                                    \
      : "=&v"((dst)[0]), "=&v"((dst)[1]), "=&v"((dst)[2]), "=&v"((dst)[3]),   \
        "=&v"((dst)[4]), "=&v"((dst)[5]), "=&v"((dst)[6]), "=&v"((dst)[7]),   \
        "=&v"((dst)[8]), "=&v"((dst)[9]), "=&v"((dst)[10]), "=&v"((dst)[11]), \
        "=&v"((dst)[12]), "=&v"((dst)[13]), "=&v"((dst)[14]), "=&v"((dst)[15])\
      : "v"(base)                                                             \
      : "memory")

// Vectorized prep: 8-wide conversions everywhere (2x float4 load -> 16B store).
__global__ void prep_kernel(const float* __restrict__ x, const float* __restrict__ h0,
                            const float* __restrict__ Wf, const float* __restrict__ Wi,
                            const float* __restrict__ Wg, const float* __restrict__ Wo,
                            __bf16* __restrict__ x_bf, __bf16* __restrict__ w_x,
                            __bf16* __restrict__ w_h, __bf16* __restrict__ h_buf,
                            int* __restrict__ bar) {
  size_t tid = (size_t)blockIdx.x * blockDim.x + threadIdx.x;
  size_t stride = (size_t)gridDim.x * blockDim.x;     // 524288 threads

  // x: f32 -> bf16, 8 elems/iter
  for (size_t i = tid; i < (size_t)(SBH / 8); i += stride) {
    const float4* s = (const float4*)x + i * 2;
    ((u32x4*)x_bf)[i] = cvt8(s[0], s[1]);
  }

  // weights: 4 matrices x 1024 rows x 128 chunks-of-8. Split k<1024 -> w_x, else w_h.
  const float* Ws[4] = {Wf, Wi, Wg, Wo};
  for (size_t i = tid; i < (size_t)(4 * 1024 * 128); i += stride) {
    int g   = (int)(i >> 17);
    int rem = (int)(i & 131071);
    int j   = rem >> 7;
    int kc8 = rem & 127;
    const float* row = Ws[g] + (size_t)j * 2048;
    const float4* sx = (const float4*)(row + kc8 * 8);
    const float4* sh = (const float4*)(row + 1024 + kc8 * 8);
    size_t dst = (size_t)(g * 1024 + j) * 128 + kc8;
    ((u32x4*)w_x)[dst] = cvt8(sx[0], sx[1]);
    ((u32x4*)w_h)[dst] = cvt8(sh[0], sh[1]);
  }

  // h0 -> bf16 (first h_buf half only; t=0 reads roff=0)
  for (size_t i = tid; i < (size_t)(BH / 8); i += stride) {
    const float4* s = (const float4*)h0 + i * 2;
    ((u32x4*)h_buf)[i] = cvt8(s[0], s[1]);
  }

  for (size_t i = tid; i < BAR_INTS; i += stride) bar[i] = 0;
}

// 256 WGs x 256 thr (1 WG/CU). WG: M=16 batches x N=64 gate-cols (16 units x 4 gates).
// Wave w owns K-quarter: w0/w1 = h k[0,512)/[512,1024) (LLC sc0sc1 loads);
// w2/w3 = x (cached loads). B: 64 frags resident (asm-pinned, may spill to AGPRs).
// A: 16 frags straight into registers per step — no LDS staging. z combined in LDS.
//
// Sync: batch-tile groups (wgid&3) are data-independent — h(t)[b-tile] is produced
// and consumed only by the 64 WGs sharing that tile. So: 4 INDEPENDENT group
// barriers, depth-2 (8 leaves x 8 arrivals -> group root; consumers poll root==8).
// No global sync, no go-flag broadcast hop, no cross-group straggler coupling.
__global__ __launch_bounds__(256, 1) void lstm_kernel(
    const float* __restrict__ x, const float* __restrict__ c0,
    const float* __restrict__ bfp, const float* __restrict__ bip,
    const float* __restrict__ bgp, const float* __restrict__ bop,
    const __bf16* __restrict__ x_bf, const __bf16* __restrict__ w_x,
    const __bf16* __restrict__ w_h, __bf16* __restrict__ h_buf,
    int* __restrict__ bar, float* __restrict__ out) {
  const int tid    = threadIdx.x;
  const int wgid   = blockIdx.x;
  const int m_idx  = wgid & 3;           // batch-tile group (independent chains)
  const int m_base = m_idx * 16;         // batch tile: 0/16/32/48
  const int U      = (wgid >> 2) * 16;   // 16 hidden units per WG
  const int wave   = tid >> 6;           // K-quarter owner
  const int lane   = tid & 63;
  const int l16    = lane & 15;
  const int kq8    = (lane >> 4) * 8;
  const int sub    = (wgid >> 2) & 7;    // leaf within group: 8 leaves x 8 WGs

  int* mycnt  = bar + (m_idx * 8 + sub) * 256;  // leaf counter line (per t)
  int* myroot = bar + 8192 + m_idx * 256;       // group root counter (per t)

  __shared__ float zbuf[4][16][65];      // per-wave partial z tiles (padded stride 65)

  // ---- Resident B: 64 frags (4 gates x 16 kc), one safe asm block per gate ----
  u32x4 Braw[64];
  {
    const __bf16* wsrc = (wave < 2) ? w_h : w_x;
    const int kbase = (wave & 1) * 512;
#pragma unroll
    for (int n = 0; n < 4; ++n) {
      unsigned long gb =
          (unsigned long)(wsrc + (size_t)(n * 1024 + U + l16) * HID + kbase + kq8);
      LOAD16_X4(&Braw[n * 16], gb, "");
    }
  }

  // ---- Per-thread state: (b_loc = tid>>4, u_loc = tid&15) ----
  const int b_loc  = tid >> 4;
  const int u_loc  = tid & 15;
  const int j_t    = U + u_loc;
  const int b_glob = m_base + b_loc;
  float c = c0[(size_t)b_glob * HID + j_t];
  const float bias_f = bfp[j_t], bias_i = bip[j_t], bias_g = bgp[j_t], bias_o = bop[j_t];

  for (int t = 0; t < S_LEN; ++t) {
    const size_t roff = (t & 1) ? (size_t)BH : 0;
    const size_t woff = (t & 1) ? 0 : (size_t)BH;

    // ---- A frags straight to registers (no LDS) ----
    u32x4 Araw[16];
    if (wave < 2) {
      unsigned long ga = (unsigned long)(h_buf + roff + (size_t)(m_base + l16) * HID +
                                         (wave & 1) * 512 + kq8);
      LOAD16_X4(Araw, ga, "sc0 sc1");
    } else {
      const __bf16* xp =
          x_bf + ((size_t)(t * BATCH + m_base + l16)) * HID + (wave & 1) * 512 + kq8;
#pragma unroll
      for (int kc = 0; kc < 16; ++kc) Araw[kc] = *(const u32x4*)(xp + kc * 32);
    }

    // ---- 64 MFMAs: 4 independent gate chains ----
    f32x4 acc0 = {0,0,0,0}, acc1 = {0,0,0,0}, acc2 = {0,0,0,0}, acc3 = {0,0,0,0};
#pragma unroll
    for (int kc = 0; kc < 16; ++kc) {
      bf16x8 a = __builtin_bit_cast(bf16x8, Araw[kc]);
      acc0 = __builtin_amdgcn_mfma_f32_16x16x32_bf16(a, __builtin_bit_cast(bf16x8, Braw[ 0 + kc]), acc0, 0, 0, 0);
      acc1 = __builtin_amdgcn_mfma_f32_16x16x32_bf16(a, __builtin_bit_cast(bf16x8, Braw[16 + kc]), acc1, 0, 0, 0);
      acc2 = __builtin_amdgcn_mfma_f32_16x16x32_bf16(a, __builtin_bit_cast(bf16x8, Braw[32 + kc]), acc2, 0, 0, 0);
      acc3 = __builtin_amdgcn_mfma_f32_16x16x32_bf16(a, __builtin_bit_cast(bf16x8, Braw[48 + kc]), acc3, 0, 0, 0);
    }

    // ---- z partials to LDS: C/D row = quad*4+r (batch-local), col = gate*16 + l16 ----
    {
      int q = lane >> 4;
#pragma unroll
      for (int r = 0; r < 4; ++r) {
        zbuf[wave][q * 4 + r][ 0 + l16] = acc0[r];
        zbuf[wave][q * 4 + r][16 + l16] = acc1[r];
        zbuf[wave][q * 4 + r][32 + l16] = acc2[r];
        zbuf[wave][q * 4 + r][48 + l16] = acc3[r];
      }
    }
    __syncthreads();

    // ---- Combine gates, update c, h; store h to coherence point ----
    float h;
    {
      float zf = 0.f, zi = 0.f, zg = 0.f, zo = 0.f;
#pragma unroll
      for (int w = 0; w < 4; ++w) {
        zf += zbuf[w][b_loc][ 0 + u_loc];
        zi += zbuf[w][b_loc][16 + u_loc];
        zg += zbuf[w][b_loc][32 + u_loc];
        zo += zbuf[w][b_loc][48 + u_loc];
      }
      float fg = sigm(zf + bias_f);
      float ig = sigm(zi + bias_i);
      float gg = tanh_fast(zg + bias_g);
      float og = sigm(zo + bias_o);
      c = fg * c + ig * gg;
      h = og * tanh_fast(c);
      if (t < S_LEN - 1) {
        __bf16 hb16 = (__bf16)h;
        unsigned short hbits = __builtin_bit_cast(unsigned short, hb16);
        __hip_atomic_store((unsigned short*)(h_buf + woff + (size_t)b_glob * HID + j_t),
                           hbits, __ATOMIC_RELAXED, __HIP_MEMORY_SCOPE_AGENT);
      }
    }

    if (t < S_LEN - 1) {
      // ---- Per-group barrier; out-write overlaps the spin ----
      __syncthreads();   // vmcnt(0): h stores complete before arrive
      if (tid == 0) {
        int old = __hip_atomic_fetch_add(&mycnt[t], 1,
                                         __ATOMIC_RELAXED, __HIP_MEMORY_SCOPE_AGENT);
        if (old == 7) {
          __hip_atomic_fetch_add(&myroot[t], 1,
                                 __ATOMIC_RELAXED, __HIP_MEMORY_SCOPE_AGENT);
        }
      }
      {
        size_t oi = ((size_t)(t * BATCH + b_glob)) * HID + j_t;
        out[oi] = x[oi] + h;
      }
      if (tid == 0) {
        while (__hip_atomic_load(&myroot[t],
                                 __ATOMIC_RELAXED, __HIP_MEMORY_SCOPE_AGENT) < 8) {
          __builtin_amdgcn_s_sleep(1);
        }
      }
      __syncthreads();
    } else {
      size_t oi = ((size_t)(t * BATCH + b_glob)) * HID + j_t;
      out[oi] = x[oi] + h;
      out[(size_t)SBH + (size_t)b_glob * HID + j_t] = h;         // h_f
      out[(size_t)SBH + BH + (size_t)b_glob * HID + j_t] = c;    // c_f
    }
  }
}

extern "C" void kernel_launch(void* const* d_in, const int* in_sizes, int n_in,
                              void* d_out, int out_size, void* d_ws, size_t ws_size,
                              hipStream_t stream) {
  const float* x   = (const float*)d_in[0];
  const float* h0  = (const float*)d_in[1];
  const float* c0  = (const float*)d_in[2];
  const float* Wf  = (const float*)d_in[3];
  const float* bf_ = (const float*)d_in[4];
  const float* Wi  = (const float*)d_in[5];
  const float* bi_ = (const float*)d_in[6];
  const float* Wg  = (const float*)d_in[7];
  const float* bg_ = (const float*)d_in[8];
  const float* Wo  = (const float*)d_in[9];
  const float* bo_ = (const float*)d_in[10];

  char* ws = (char*)d_ws;
  size_t off = 0;
  __bf16* x_bf = (__bf16*)(ws + off); off += (size_t)SBH * 2;              // 32 MB
  __bf16* w_x  = (__bf16*)(ws + off); off += (size_t)4 * 1024 * 1024 * 2;  // 8 MB
  __bf16* w_h  = (__bf16*)(ws + off); off += (size_t)4 * 1024 * 1024 * 2;  // 8 MB
  __bf16* h_buf = (__bf16*)(ws + off); off += (size_t)2 * BH * 2;          // 256 KB
  int* bar = (int*)(ws + off); off += BAR_INTS * sizeof(int);
  if (ws_size < off) return;

  float* out = (float*)d_out;

  prep_kernel<<<2048, 256, 0, stream>>>(x, h0, Wf, Wi, Wg, Wo, x_bf, w_x, w_h, h_buf, bar);
  lstm_kernel<<<NWG, 256, 0, stream>>>(x, c0, bf_, bi_, bg_, bo_, x_bf, w_x, w_h, h_buf, bar, out);
}

// Round 2
// 1148.826 us; speedup vs baseline: 1.2818x; 1.2818x over previous
//
#include <hip/hip_runtime.h>

typedef __bf16 bf16x8 __attribute__((ext_vector_type(8)));
typedef float f32x4 __attribute__((ext_vector_type(4)));
typedef unsigned int u32x4 __attribute__((ext_vector_type(4)));

#define S_LEN 256
#define BATCH 64
#define HID   1024
#define NWG   256
#define SBH   (S_LEN * BATCH * HID)   /* 16777216 */
#define BH    (BATCH * HID)           /* 65536 */
/* bar layout (ints): slots[4][64] at 0. Monotone per-WG step counters, no reset. */
#define BAR_INTS 256

__device__ __forceinline__ float sigm(float v) { return 1.0f / (1.0f + __expf(-v)); }
__device__ __forceinline__ float tanh_fast(float v) {
  float e = __expf(-2.0f * __builtin_fabsf(v));
  float r = (1.0f - e) / (1.0f + e);
  return __builtin_copysignf(r, v);
}

// Pack 8 f32 -> 8 bf16 (RNE via compiler cvt) into one 16B word.
__device__ __forceinline__ u32x4 cvt8(float4 a, float4 b) {
  union { unsigned short us[8]; u32x4 v; } r;
  r.us[0] = __builtin_bit_cast(unsigned short, (__bf16)a.x);
  r.us[1] = __builtin_bit_cast(unsigned short, (__bf16)a.y);
  r.us[2] = __builtin_bit_cast(unsigned short, (__bf16)a.z);
  r.us[3] = __builtin_bit_cast(unsigned short, (__bf16)a.w);
  r.us[4] = __builtin_bit_cast(unsigned short, (__bf16)b.x);
  r.us[5] = __builtin_bit_cast(unsigned short, (__bf16)b.y);
  r.us[6] = __builtin_bit_cast(unsigned short, (__bf16)b.z);
  r.us[7] = __builtin_bit_cast(unsigned short, (__bf16)b.w);
  return r.v;
}

// One asm block: 16 x global_load_dwordx4 from base %16 + kc*64B, then vmcnt(0).
// Early-clobber outputs + internal waitcnt => no compiler copy can read in-flight regs.
#define LOAD16_X4(dst, base, MODS)                                            \
  asm volatile(                                                               \
      "global_load_dwordx4 %0,  %16, off offset:0 " MODS "\n\t"               \
      "global_load_dwordx4 %1,  %16, off offset:64 " MODS "\n\t"              \
      "global_load_dwordx4 %2,  %16, off offset:128 " MODS "\n\t"             \
      "global_load_dwordx4 %3,  %16, off offset:192 " MODS "\n\t"             \
      "global_load_dwordx4 %4,  %16, off offset:256 " MODS "\n\t"             \
      "global_load_dwordx4 %5,  %16, off offset:320 " MODS "\n\t"             \
      "global_load_dwordx4 %6,  %16, off offset:384 " MODS "\n\t"             \
      "global_load_dwordx4 %7,  %16, off offset:448 " MODS "\n\t"             \
      "global_load_dwordx4 %8,  %16, off offset:512 " MODS "\n\t"             \
      "global_load_dwordx4 %9,  %16, off offset:576 " MODS "\n\t"             \
      "global_load_dwordx4 %10, %16, off offset:640 " MODS "\n\t"             \
      "global_load_dwordx4 %11, %16, off offset:704 " MODS "\n\t"             \
      "global_load_dwordx4 %12, %16, off offset:768 " MODS "\n\t"             \
      "global_load_dwordx4 %13, %16, off offset:832 " MODS "\n\t"             \
      "global_load_dwordx4 %14, %16, off offset:896 " MODS "\n\t"             \
      "global_load_dwordx4 %15, %16, off offset:960 " MODS "\n\t"             \
      "s_waitcnt vmcnt(0)"                                                    \
      : "=&v"((dst)[0]), "=&v"((dst)[1]), "=&v"((dst)[2]), "=&v"((dst)[3]),   \
        "=&v"((dst)[4]), "=&v"((dst)[5]), "=&v"((dst)[6]), "=&v"((dst)[7]),   \
        "=&v"((dst)[8]), "=&v"((dst)[9]), "=&v"((dst)[10]), "=&v"((dst)[11]), \
        "=&v"((dst)[12]), "=&v"((dst)[13]), "=&v"((dst)[14]), "=&v"((dst)[15])\
      : "v"(base)                                                             \
      : "memory")

// Vectorized prep: 8-wide conversions, compile-time weight pointers (no scratch array).
__global__ void prep_kernel(const float* __restrict__ x, const float* __restrict__ h0,
                            const float* __restrict__ Wf, const float* __restrict__ Wi,
                            const float* __restrict__ Wg, const float* __restrict__ Wo,
                            __bf16* __restrict__ x_bf, __bf16* __restrict__ w_x,
                            __bf16* __restrict__ w_h, __bf16* __restrict__ h_buf,
                            int* __restrict__ bar) {
  size_t tid = (size_t)blockIdx.x * blockDim.x + threadIdx.x;
  size_t stride = (size_t)gridDim.x * blockDim.x;     // 524288 threads

  // x: f32 -> bf16, 8 elems/iter
  for (size_t i = tid; i < (size_t)(SBH / 8); i += stride) {
    const float4* s = (const float4*)x + i * 2;
    ((u32x4*)x_bf)[i] = cvt8(s[0], s[1]);
  }

  // weights: compile-time matrix pointer per loop (runtime-indexed ptr array -> scratch).
#define W_CONV(W, gidx)                                                        \
  for (size_t i = tid; i < (size_t)(1024 * 128); i += stride) {                \
    int j   = (int)(i >> 7);                                                   \
    int kc8 = (int)(i & 127);                                                  \
    const float* row = (W) + (size_t)j * 2048;                                 \
    const float4* sx = (const float4*)(row + kc8 * 8);                         \
    const float4* sh = (const float4*)(row + 1024 + kc8 * 8);                  \
    size_t dst = (size_t)((gidx) * 1024 + j) * 128 + kc8;                      \
    ((u32x4*)w_x)[dst] = cvt8(sx[0], sx[1]);                                   \
    ((u32x4*)w_h)[dst] = cvt8(sh[0], sh[1]);                                   \
  }
  W_CONV(Wf, 0)
  W_CONV(Wi, 1)
  W_CONV(Wg, 2)
  W_CONV(Wo, 3)
#undef W_CONV

  // h0 -> bf16 (first h_buf half only; t=0 reads roff=0)
  for (size_t i = tid; i < (size_t)(BH / 8); i += stride) {
    const float4* s = (const float4*)h0 + i * 2;
    ((u32x4*)h_buf)[i] = cvt8(s[0], s[1]);
  }

  for (size_t i = tid; i < BAR_INTS; i += stride) bar[i] = 0;
}

// 256 WGs x 256 thr (1 WG/CU). WG: M=16 batches x N=64 gate-cols (16 units x 4 gates).
// Wave w owns K-quarter: w0/w1 = h k[0,512)/[512,1024) (LLC sc0sc1 loads);
// w2/w3 = x (cached loads). B: 64 frags resident (asm-pinned, may spill to AGPRs).
// A: 16 frags straight into registers per step — no LDS staging. z combined in LDS.
//
// Sync (v2): ZERO-RMW store/ballot barrier, per batch-tile group (64 WGs, data-
// independent across groups). Each WG publishes slots[wg] = t+1 (plain relaxed
// store, monotone — no reset, no per-t arrays). Wave 0 polls its group's 64 slots
// with ONE coalesced 256B load (lane l reads slot l) + __ballot(v >= t+1).
// Removes leaf-RMW + root-RMW + go-store hops; poll traffic is read-only.
// Monotonicity makes it safe for a fast WG to run 1 step ahead (it only overwrites
// the h half-buffer all group members have already consumed).
//
// x-side latency hiding: waves 2/3 never read h, so their x tile for step t+1 is
// issued BEFORE the poll; the closing __syncthreads' vmcnt(0) lands them under
// the spin.
__global__ __launch_bounds__(256, 1) void lstm_kernel(
    const float* __restrict__ x, const float* __restrict__ c0,
    const float* __restrict__ bfp, const float* __restrict__ bip,
    const float* __restrict__ bgp, const float* __restrict__ bop,
    const __bf16* __restrict__ x_bf, const __bf16* __restrict__ w_x,
    const __bf16* __restrict__ w_h, __bf16* __restrict__ h_buf,
    int* __restrict__ bar, float* __restrict__ out) {
  const int tid    = threadIdx.x;
  const int wgid   = blockIdx.x;
  const int m_idx  = wgid & 3;           // batch-tile group (independent chains)
  const int m_base = m_idx * 16;         // batch tile: 0/16/32/48
  const int U      = (wgid >> 2) * 16;   // 16 hidden units per WG
  const int wave   = tid >> 6;           // K-quarter owner
  const int lane   = tid & 63;
  const int l16    = lane & 15;
  const int kq8    = (lane >> 4) * 8;
  const int wg_in_grp = wgid >> 2;       // 0..63 within group

  int* slots   = bar + m_idx * 64;       // this group's 64 slot words (256 B)

  __shared__ float zbuf[4][16][65];      // per-wave partial z tiles (padded stride 65)

  // ---- Resident B: 64 frags (4 gates x 16 kc), one safe asm block per gate ----
  u32x4 Braw[64];
  {
    const __bf16* wsrc = (wave < 2) ? w_h : w_x;
    const int kbase = (wave & 1) * 512;
#pragma unroll
    for (int n = 0; n < 4; ++n) {
      unsigned long gb =
          (unsigned long)(wsrc + (size_t)(n * 1024 + U + l16) * HID + kbase + kq8);
      LOAD16_X4(&Braw[n * 16], gb, "");
    }
  }

  // ---- Per-thread state: (b_loc = tid>>4, u_loc = tid&15) ----
  const int b_loc  = tid >> 4;
  const int u_loc  = tid & 15;
  const int j_t    = U + u_loc;
  const int b_glob = m_base + b_loc;
  float c = c0[(size_t)b_glob * HID + j_t];
  const float bias_f = bfp[j_t], bias_i = bip[j_t], bias_g = bgp[j_t], bias_o = bop[j_t];

  // A frags live across iterations: waves 2/3 prefetch next-t x during the poll.
  u32x4 Araw[16];
  if (wave >= 2) {
    const __bf16* xp =
        x_bf + ((size_t)(0 * BATCH + m_base + l16)) * HID + (wave & 1) * 512 + kq8;
#pragma unroll
    for (int kc = 0; kc < 16; ++kc) Araw[kc] = *(const u32x4*)(xp + kc * 32);
  }

  for (int t = 0; t < S_LEN; ++t) {
    const size_t roff = (t & 1) ? (size_t)BH : 0;
    const size_t woff = (t & 1) ? 0 : (size_t)BH;

    // ---- h frags straight to registers (waves 0/1); x already prefetched ----
    if (wave < 2) {
      unsigned long ga = (unsigned long)(h_buf + roff + (size_t)(m_base + l16) * HID +
                                         (wave & 1) * 512 + kq8);
      LOAD16_X4(Araw, ga, "sc0 sc1");
    }

    // ---- 64 MFMAs: 4 independent gate chains ----
    f32x4 acc0 = {0,0,0,0}, acc1 = {0,0,0,0}, acc2 = {0,0,0,0}, acc3 = {0,0,0,0};
#pragma unroll
    for (int kc = 0; kc < 16; ++kc) {
      bf16x8 a = __builtin_bit_cast(bf16x8, Araw[kc]);
      acc0 = __builtin_amdgcn_mfma_f32_16x16x32_bf16(a, __builtin_bit_cast(bf16x8, Braw[ 0 + kc]), acc0, 0, 0, 0);
      acc1 = __builtin_amdgcn_mfma_f32_16x16x32_bf16(a, __builtin_bit_cast(bf16x8, Braw[16 + kc]), acc1, 0, 0, 0);
      acc2 = __builtin_amdgcn_mfma_f32_16x16x32_bf16(a, __builtin_bit_cast(bf16x8, Braw[32 + kc]), acc2, 0, 0, 0);
      acc3 = __builtin_amdgcn_mfma_f32_16x16x32_bf16(a, __builtin_bit_cast(bf16x8, Braw[48 + kc]), acc3, 0, 0, 0);
    }

    // ---- z partials to LDS: C/D row = quad*4+r (batch-local), col = gate*16 + l16 ----
    {
      int q = lane >> 4;
#pragma unroll
      for (int r = 0; r < 4; ++r) {
        zbuf[wave][q * 4 + r][ 0 + l16] = acc0[r];
        zbuf[wave][q * 4 + r][16 + l16] = acc1[r];
        zbuf[wave][q * 4 + r][32 + l16] = acc2[r];
        zbuf[wave][q * 4 + r][48 + l16] = acc3[r];
      }
    }
    __syncthreads();

    // ---- Combine gates, update c, h; store h to coherence point ----
    float h;
    {
      float zf = 0.f, zi = 0.f, zg = 0.f, zo = 0.f;
#pragma unroll
      for (int w = 0; w < 4; ++w) {
        zf += zbuf[w][b_loc][ 0 + u_loc];
        zi += zbuf[w][b_loc][16 + u_loc];
        zg += zbuf[w][b_loc][32 + u_loc];
        zo += zbuf[w][b_loc][48 + u_loc];
      }
      float fg = sigm(zf + bias_f);
      float ig = sigm(zi + bias_i);
      float gg = tanh_fast(zg + bias_g);
      float og = sigm(zo + bias_o);
      c = fg * c + ig * gg;
      h = og * tanh_fast(c);
      if (t < S_LEN - 1) {
        __bf16 hb16 = (__bf16)h;
        unsigned short hbits = __builtin_bit_cast(unsigned short, hb16);
        __hip_atomic_store((unsigned short*)(h_buf + woff + (size_t)b_glob * HID + j_t),
                           hbits, __ATOMIC_RELAXED, __HIP_MEMORY_SCOPE_AGENT);
      }
    }

    if (t < S_LEN - 1) {
      // ---- Publish completion; overlap out-write + x-prefetch with the poll ----
      __syncthreads();   // each wave's vmcnt(0): all h stores of this WG complete
      if (tid == 0) {
        __hip_atomic_store(&slots[wg_in_grp], t + 1,
                           __ATOMIC_RELAXED, __HIP_MEMORY_SCOPE_AGENT);
      }
      {
        size_t oi = ((size_t)(t * BATCH + b_glob)) * HID + j_t;
        out[oi] = x[oi] + h;
      }
      if (wave >= 2) {
        // next step's x tile: in flight during the poll, landed by the barrier
        const __bf16* xp = x_bf +
            ((size_t)((t + 1) * BATCH + m_base + l16)) * HID + (wave & 1) * 512 + kq8;
#pragma unroll
        for (int kc = 0; kc < 16; ++kc) Araw[kc] = *(const u32x4*)(xp + kc * 32);
      }
      if (wave == 0) {
        const int target = t + 1;
        while (true) {
          int v = __hip_atomic_load(&slots[lane],
                                    __ATOMIC_RELAXED, __HIP_MEMORY_SCOPE_AGENT);
          if (__ballot(v >= target) == ~0ull) break;
          __builtin_amdgcn_s_sleep(1);
        }
      }
      __syncthreads();
    } else {
      size_t oi = ((size_t)(t * BATCH + b_glob)) * HID + j_t;
      out[oi] = x[oi] + h;
      out[(size_t)SBH + (size_t)b_glob * HID + j_t] = h;         // h_f
      out[(size_t)SBH + BH + (size_t)b_glob * HID + j_t] = c;    // c_f
    }
  }
}

extern "C" void kernel_launch(void* const* d_in, const int* in_sizes, int n_in,
                              void* d_out, int out_size, void* d_ws, size_t ws_size,
                              hipStream_t stream) {
  const float* x   = (const float*)d_in[0];
  const float* h0  = (const float*)d_in[1];
  const float* c0  = (const float*)d_in[2];
  const float* Wf  = (const float*)d_in[3];
  const float* bf_ = (const float*)d_in[4];
  const float* Wi  = (const float*)d_in[5];
  const float* bi_ = (const float*)d_in[6];
  const float* Wg  = (const float*)d_in[7];
  const float* bg_ = (const float*)d_in[8];
  const float* Wo  = (const float*)d_in[9];
  const float* bo_ = (const float*)d_in[10];

  char* ws = (char*)d_ws;
  size_t off = 0;
  __bf16* x_bf = (__bf16*)(ws + off); off += (size_t)SBH * 2;              // 32 MB
  __bf16* w_x  = (__bf16*)(ws + off); off += (size_t)4 * 1024 * 1024 * 2;  // 8 MB
  __bf16* w_h  = (__bf16*)(ws + off); off += (size_t)4 * 1024 * 1024 * 2;  // 8 MB
  __bf16* h_buf = (__bf16*)(ws + off); off += (size_t)2 * BH * 2;          // 256 KB
  int* bar = (int*)(ws + off); off += BAR_INTS * sizeof(int);
  if (ws_size < off) return;

  float* out = (float*)d_out;

  prep_kernel<<<2048, 256, 0, stream>>>(x, h0, Wf, Wi, Wg, Wo, x_bf, w_x, w_h, h_buf, bar);
  lstm_kernel<<<NWG, 256, 0, stream>>>(x, c0, bf_, bi_, bg_, bo_, x_bf, w_x, w_h, h_buf, bar, out);
}